// Round 11
// baseline (193.644 us; speedup 1.0000x reference)
//
#include <hip/hip_runtime.h>
#include <hip/hip_bf16.h>
#include <math.h>

// ---------------- problem constants (fixed instance) ----------------
constexpr int Bn   = 8;
constexpr int Hh   = 64;
constexpr int Ww   = 64;
constexpr int Nn   = Hh * Ww;      // 4096
constexpr int Mrows = Bn * Nn;     // 32768
constexpr int QKVC = 512;          // qv channels
constexpr int DIMc = 256;

typedef short short8 __attribute__((ext_vector_type(8)));
typedef float f32x16 __attribute__((ext_vector_type(16)));
typedef float f32x4 __attribute__((ext_vector_type(4)));

__device__ __forceinline__ float hswish(float x) {
    float r = fminf(fmaxf(x + 3.f, 0.f), 6.f);
    return x * r * (1.f / 6.f);
}

__device__ __forceinline__ ushort bf16u(float f) {
    return __bfloat16_as_ushort(__float2bfloat16(f));
}

__device__ __forceinline__ uint32_t pkbf(float a, float b) {
    return (uint32_t)bf16u(a) | ((uint32_t)bf16u(b) << 16);
}

// HW packed bf16 convert (RNE): lo=cvt(a), hi=cvt(b) — no builtin, asm only
__device__ __forceinline__ uint32_t cvtpk(float a, float b) {
    uint32_t r;
    asm("v_cvt_pk_bf16_f32 %0, %1, %2" : "=v"(r) : "v"(a), "v"(b));
    return r;
}

// packed bf16 dot2: c += a.lo*b.lo + a.hi*b.hi   (v_dot2_f32_bf16, CDNA3/4)
__device__ __forceinline__ float dot2bf(uint32_t a, uint32_t b, float c) {
    asm("v_dot2_f32_bf16 %0, %1, %2, %0" : "+v"(c) : "v"(a), "v"(b));
    return c;
}

__device__ __forceinline__ float bflo(uint32_t p) {
    union { uint32_t u; float f; } c; c.u = p << 16; return c.f;
}
__device__ __forceinline__ float bfhi(uint32_t p) {
    union { uint32_t u; float f; } c; c.u = p & 0xFFFF0000u; return c.f;
}

#if __has_builtin(__builtin_amdgcn_permlane32_swap)
typedef int int2v __attribute__((ext_vector_type(2)));
__device__ __forceinline__ void plswap(uint32_t& a, uint32_t& b) {
    int2v r = __builtin_amdgcn_permlane32_swap((int)a, (int)b, false, false);
    a = (uint32_t)r.x; b = (uint32_t)r.y;
}
#else
__device__ __forceinline__ void plswap(uint32_t& a, uint32_t& b) {
    int l = threadIdx.x & 63;
    uint32_t sa = (uint32_t)__shfl_xor((int)a, 32);
    uint32_t sb = (uint32_t)__shfl_xor((int)b, 32);
    uint32_t na = (l < 32) ? a : sb;
    uint32_t nb = (l < 32) ? sa : b;
    a = na; b = nb;
}
#endif

__device__ __forceinline__ void gload_lds16(const ushort* g, ushort* l) {
    __builtin_amdgcn_global_load_lds(
        (const __attribute__((address_space(1))) unsigned int*)g,
        (__attribute__((address_space(3))) unsigned int*)l, 16, 0, 0);
}

// ---------------- bf16 convert: xb = bf16(x) ----------------
__global__ __launch_bounds__(256) void cvtbf_kernel(
    const float* __restrict__ in, ushort* __restrict__ out)
{
    int i = (blockIdx.x * 256 + threadIdx.x) * 8;
    float4 f0 = *reinterpret_cast<const float4*>(&in[i]);
    float4 f1 = *reinterpret_cast<const float4*>(&in[i + 4]);
    float v[8] = {f0.x, f0.y, f0.z, f0.w, f1.x, f1.y, f1.z, f1.w};
    ushort o[8];
    #pragma unroll
    for (int j = 0; j < 8; ++j) o[j] = bf16u(v[j]);
    *reinterpret_cast<short8*>(&out[i]) = *reinterpret_cast<short8*>(o);
}

// ---------------- weight transpose + bf16 convert: Wt[n][k] = bf16(W[k][n]) ----------------
__global__ __launch_bounds__(256) void wtconv_kernel(
    const float* __restrict__ Wf, ushort* __restrict__ Wt, int K, int N)
{
    int idx = blockIdx.x * 256 + threadIdx.x;   // k fast
    int n = idx / K, k = idx - n * K;
    Wt[idx] = bf16u(Wf[(size_t)k * N + n]);
}

// ---------------- effective conv weights, packed bf16 (q|v) ----------------
__global__ __launch_bounds__(256) void weff_kernel(
    const float* __restrict__ dw, const float* __restrict__ fcw,
    uint32_t* __restrict__ Wp)
{
    int idx = blockIdx.x * 256 + threadIdx.x;   // 9216
    if (idx >= 9216) return;
    int k = idx % 9;
    int a = (idx / 9) & 7;
    int oc = (idx / 72) & 7;
    int gi = idx / 576;
    float q = 0.f, v = 0.f;
    const float* dwp = &dw[(gi * 8 + oc) * 81 + k];
    #pragma unroll
    for (int ic = 0; ic < 9; ++ic) {
        float d = dwp[ic * 9];
        q += d * fcw[ic * 24 + a];
        v += d * (fcw[ic * 24 + 8 + a] + fcw[ic * 24 + 16 + a]);
    }
    Wp[idx] = pkbf(q, v);
}

// ---------------- bf16 MFMA GEMM: C = A[M,K] @ Bt[N,K]^T + bias ----------------
template<bool OBF, bool STATS>
__global__ __launch_bounds__(256) void hgemm_kernel(
    const ushort* __restrict__ A, const ushort* __restrict__ Bt,
    const float* __restrict__ bias, void* __restrict__ Cv,
    float* __restrict__ stats, int M, int N, int K)
{
    __shared__ ushort As[128 * 32];
    __shared__ ushort Bs[128 * 32];
    const int tid = threadIdx.x;
    const int w = tid >> 6, l = tid & 63;
    const int brow = blockIdx.y * 128;
    const int bcol = blockIdx.x * 128;
    const int wm = (w >> 1) * 64, wn = (w & 1) * 64;

    f32x4 acc[4][4] = {};

    const int c0 = tid, c1 = tid + 256;
    const int r0 = c0 >> 2, q0 = (c0 & 3) ^ (r0 & 3);
    const int r1 = c1 >> 2, q1 = (c1 & 3) ^ (r1 & 3);
    const ushort* a0p = &A[(size_t)(brow + r0) * K + q0 * 8];
    const ushort* a1p = &A[(size_t)(brow + r1) * K + q1 * 8];
    const ushort* b0p = &Bt[(size_t)(bcol + r0) * K + q0 * 8];
    const ushort* b1p = &Bt[(size_t)(bcol + r1) * K + q1 * 8];
    ushort* asw0 = &As[(w * 64) * 8];
    ushort* asw1 = &As[(256 + w * 64) * 8];
    ushort* bsw0 = &Bs[(w * 64) * 8];
    ushort* bsw1 = &Bs[(256 + w * 64) * 8];

    const int fr = l & 15;
    const int qq = ((l >> 4) ^ (l & 3)) * 8;

    for (int k0 = 0; k0 < K; k0 += 32) {
        gload_lds16(a0p + k0, asw0);
        gload_lds16(a1p + k0, asw1);
        gload_lds16(b0p + k0, bsw0);
        gload_lds16(b1p + k0, bsw1);
        __syncthreads();
        short8 af[4], bf[4];
        #pragma unroll
        for (int i = 0; i < 4; ++i) {
            af[i] = *reinterpret_cast<const short8*>(&As[(wm + i * 16 + fr) * 32 + qq]);
            bf[i] = *reinterpret_cast<const short8*>(&Bs[(wn + i * 16 + fr) * 32 + qq]);
        }
        #pragma unroll
        for (int mi = 0; mi < 4; ++mi)
            #pragma unroll
            for (int ni = 0; ni < 4; ++ni)
                acc[mi][ni] = __builtin_amdgcn_mfma_f32_16x16x32_bf16(
                    af[mi], bf[ni], acc[mi][ni], 0, 0, 0);
        __syncthreads();
    }

    const int cr = l >> 4;
    #pragma unroll
    for (int ni = 0; ni < 4; ++ni) {
        int n = bcol + wn + ni * 16 + fr;
        float bv = bias[n];
        float s1 = 0.f, s2 = 0.f;
        #pragma unroll
        for (int mi = 0; mi < 4; ++mi) {
            int m = brow + wm + mi * 16 + cr * 4;
            #pragma unroll
            for (int r = 0; r < 4; ++r) {
                float val = acc[mi][ni][r] + bv;
                if (OBF)
                    ((ushort*)Cv)[(size_t)(m + r) * N + n] = bf16u(val);
                else
                    ((float*)Cv)[(size_t)(m + r) * N + n] = val;
                if (STATS) { s1 += val; s2 += val * val; }
            }
        }
        if (STATS) {
            s1 += __shfl_xor(s1, 16); s2 += __shfl_xor(s2, 16);
            s1 += __shfl_xor(s1, 32); s2 += __shfl_xor(s2, 32);
            if (cr == 0) {
                atomicAdd(&stats[n], s1);
                atomicAdd(&stats[256 + n], s2);
            }
        }
    }
}

// ---------------- depthwise 3x3 on hard_swish(v): Abuf(bf16) += v_conv ----------------
__global__ __launch_bounds__(256) void vconv_kernel(
    const ushort* __restrict__ qvb, const float* __restrict__ pw,
    const float* __restrict__ pb, ushort* __restrict__ Abuf)
{
    int idx = blockIdx.x * 256 + threadIdx.x;   // Mrows*128
    int c2 = idx & 127;
    int n = (idx >> 7) & (Nn - 1);
    int b = idx >> 19;
    int x = n & 63, y = n >> 6;
    int ch = c2 * 2;
    float s0 = pb[ch], s1 = pb[ch + 1];
    float w0[9], w1[9];
    #pragma unroll
    for (int k = 0; k < 9; ++k) { w0[k] = pw[ch * 9 + k]; w1[k] = pw[ch * 9 + 9 + k]; }
    #pragma unroll
    for (int ky = 0; ky < 3; ++ky) {
        int yy = y + ky - 1;
        if (yy >= 0 && yy < Hh) {
            #pragma unroll
            for (int kx = 0; kx < 3; ++kx) {
                int xx = x + kx - 1;
                if (xx >= 0 && xx < Ww) {
                    uint32_t pk = *reinterpret_cast<const uint32_t*>(
                        &qvb[(size_t)(b * Nn + yy * Ww + xx) * QKVC + 256 + ch]);
                    s0 += hswish(bflo(pk)) * w0[ky * 3 + kx];
                    s1 += hswish(bfhi(pk)) * w1[ky * 3 + kx];
                }
            }
        }
    }
    uint32_t* ap = reinterpret_cast<uint32_t*>(&Abuf[(size_t)(b * Nn + n) * DIMc + ch]);
    uint32_t cur = *ap;
    *ap = pkbf(bflo(cur) + s0, bfhi(cur) + s1);
}

// ---------------- fused conv-attention branch v4: FIRST writer of Abuf(bf16) ----------------
__global__ __launch_bounds__(256) void convbranch_kernel(
    const ushort* __restrict__ qvb, const uint32_t* __restrict__ Wp,
    const float* __restrict__ db, const float* __restrict__ rate2p,
    ushort* __restrict__ Abuf)
{
    int blk = blockIdx.x;              // 2048
    int ytile = blk & 7;               // bits 0-2
    int gi = (blk >> 3) & 15;          // bits 3-6
    int b = (blk >> 7) & 7;            // bits 7-9
    int branch = blk >> 10;            // bit 10
    int y0 = ytile * 8;
    int qoff = branch * 128;
    int coff = branch * 128;

    __shared__ uint32_t sqv[8][10][68];   // 21.25 KB; cols: halo@1, data 2..65, halo@66
    __shared__ uint32_t wpk[8][8][9];     // 2.25 KB [oc][a][k]
    const int tid = threadIdx.x;

    if (tid < 160) {
        int r = tid >> 1;
        int col = 1 + (tid & 1) * 65;
        sqv[r / 10][r % 10][col] = 0;
    }
    {
        const int x2 = (tid & 31) * 2;
        int rr = tid >> 5;             // 0..7
        int a = 0;
        const size_t bbase = (size_t)(b * Nn) * QKVC + qoff;
        #pragma unroll
        for (int it = 0; it < 10; ++it) {
            int y = y0 + rr - 1;
            uint32_t lo = 0, hi = 0;
            if ((unsigned)y < 64u) {
                int token = (a * 16 + gi) * 32 + (y >> 1);
                size_t base = bbase + (size_t)token * QKVC + (y & 1) * 64 + x2;
                uint32_t q = *reinterpret_cast<const uint32_t*>(&qvb[base]);
                uint32_t v = *reinterpret_cast<const uint32_t*>(&qvb[base + 256]);
                lo = (q & 0xffffu) | (v << 16);
                hi = (q >> 16) | (v & 0xffff0000u);
            }
            uint2 wv; wv.x = lo; wv.y = hi;
            *reinterpret_cast<uint2*>(&sqv[a][rr][2 + x2]) = wv;
            rr += 8;
            if (rr >= 10) { rr -= 10; a += 1; }
        }
    }
    for (int i = tid; i < 576; i += 256)
        ((uint32_t*)wpk)[i] = Wp[gi * 576 + i];
    __syncthreads();

    const int x = tid & 63;
    const int w = tid >> 6;
    const int rh = (w & 1) * 4;
    const int oc0 = (w >> 1) * 4;

    float acc[4][4] = {};
    #pragma unroll 1
    for (int a = 0; a < 8; ++a) {
        uint32_t ipk[6][3];
        #pragma unroll
        for (int j = 0; j < 6; ++j) {
            const uint32_t* rp = &sqv[a][rh + j][1 + x];
            ipk[j][0] = rp[0]; ipk[j][1] = rp[1]; ipk[j][2] = rp[2];
        }
        #pragma unroll
        for (int ocl = 0; ocl < 4; ++ocl) {
            #pragma unroll
            for (int ky = 0; ky < 3; ++ky)
                #pragma unroll
                for (int kx = 0; kx < 3; ++kx) {
                    uint32_t wv = wpk[oc0 + ocl][a][ky * 3 + kx];
                    #pragma unroll
                    for (int ro = 0; ro < 4; ++ro)
                        acc[ocl][ro] = dot2bf(ipk[ro + ky][kx], wv, acc[ocl][ro]);
                }
        }
    }

    const float r2 = rate2p[0];
    float dbv[4];
    #pragma unroll
    for (int j = 0; j < 4; ++j) dbv[j] = db[gi * 8 + oc0 + j];
    #pragma unroll
    for (int ro = 0; ro < 4; ++ro) {
        int n = (y0 + rh + ro) * 64 + x;
        uint2 pk;
        pk.x = pkbf(r2 * (acc[0][ro] + dbv[0]), r2 * (acc[1][ro] + dbv[1]));
        pk.y = pkbf(r2 * (acc[2][ro] + dbv[2]), r2 * (acc[3][ro] + dbv[3]));
        *reinterpret_cast<uint2*>(
            &Abuf[(size_t)(b * Nn + n) * DIMc + coff + gi * 8 + oc0]) = pk;
    }
}

// ---------------- MFMA cross-shaped window attention (k == v, bf16 input) ----------------
// K LDS: paired-row 8-slot swizzle (conflict-free b128).  VT LDS: [d][token].
// Softmax denominator via ones-MFMA on the idle matrix pipe (accS).
// Epilogue fused: Hb = bf16(hswish(Abuf(bf16) + rate1 * o))
__global__ __launch_bounds__(512, 4) void attn_mfma_kernel(
    const ushort* __restrict__ qvb, const float* __restrict__ rate1p,
    const ushort* __restrict__ Abuf, ushort* __restrict__ Hb)
{
    int bid = blockIdx.x;
    bool hor = bid < 256;
    int lb = bid & 255;
    int hd = lb & 3;
    int g = (lb >> 2) & 7;
    int b = lb >> 5;
    int half = hor ? 0 : 128;
    int qoff = half + hd * 32;
    int kvoff = 256 + qoff;

    __shared__ __align__(16) char smem[65536];
    char* ldsK  = smem;            // 32 KB (512 rows x 64B, paired-line layout)
    char* ldsVT = smem + 32768;    // 32 KB

    const int tid = threadIdx.x;
    const float QS = 0.17677669529663687f * 1.44269504088896f;  // scale * log2(e)

    {
        int l = tid;
        int n = hor ? (g * 512 + l) : ((l & 63) * 64 + g * 8 + (l >> 6));
        const ushort* kp = &qvb[(size_t)(b * Nn + n) * QKVC + kvoff];
        uint32_t p32[16];
        #pragma unroll
        for (int j = 0; j < 4; ++j) {
            uint4 wv = *reinterpret_cast<const uint4*>(&kp[j * 8]);
            p32[j * 4 + 0] = wv.x; p32[j * 4 + 1] = wv.y;
            p32[j * 4 + 2] = wv.z; p32[j * 4 + 3] = wv.w;
        }
        // K: paired-row 8-slot swizzle
        const int kpair = l >> 1, hf = l & 1;
        #pragma unroll
        for (int gc = 0; gc < 4; ++gc) {
            int cp = (hf * 4 + gc) ^ (kpair & 7);
            uint4 w;
            w.x = p32[gc * 4 + 0]; w.y = p32[gc * 4 + 1];
            w.z = p32[gc * 4 + 2]; w.w = p32[gc * 4 + 3];
            *reinterpret_cast<uint4*>(ldsK + kpair * 128 + cp * 16) = w;
        }
        // VT: u32 writes (2 tokens/word) via DPP lane-pair exchange
        #pragma unroll
        for (int j = 0; j < 16; ++j) {
            uint32_t other = (uint32_t)__shfl_xor((int)p32[j], 1);
            uint32_t pk = hf ? ((other >> 16) | (p32[j] & 0xffff0000u))
                             : ((p32[j] & 0xffffu) | (other << 16));
            int d = 2 * j + hf;
            *reinterpret_cast<uint32_t*>(
                ldsVT + d * 1024 + ((kpair * 4) ^ ((d & 7) << 4))) = pk;
        }
    }
    __syncthreads();

    const int w = tid >> 6;
    const int lane = tid & 63;
    const int qcol = lane & 31;
    const int hh = lane >> 5;
    const float r1 = rate1p[0];
    const f32x16 fz = {0,0,0,0,0,0,0,0,0,0,0,0,0,0,0,0};
    union { uint32_t u[4]; short8 s; } onesu;
    onesu.u[0] = 0x3F803F80u; onesu.u[1] = 0x3F803F80u;
    onesu.u[2] = 0x3F803F80u; onesu.u[3] = 0x3F803F80u;
    const short8 ones = onesu.s;

    // constant K-read bases
    const int kp0 = qcol >> 1;
    const char* pK = ldsK + kp0 * 128;
    const int ca0 = ((((qcol & 1) * 4) + hh) ^ (kp0 & 7)) * 16;
    const int ca1 = ((((qcol & 1) * 4) + 2 + hh) ^ (kp0 & 7)) * 16;
    const int dvt = qcol;
    const char* pVT = ldsVT + dvt * 1024;
    const int vtx = (hh * 16) ^ ((dvt & 7) << 4);

    #pragma unroll 1
    for (int qt = 0; qt < 2; ++qt) {
        const int q0 = (w * 2 + qt) * 32;
        const int qrow = q0 + qcol;
        const int nq = hor ? (g * 512 + qrow) : ((qrow & 63) * 64 + g * 8 + (qrow >> 6));

        // Q B-frags, pre-scaled by QS
        short8 qs[2];
        #pragma unroll
        for (int t = 0; t < 2; ++t) {
            const ushort* qp = &qvb[(size_t)(b * Nn + nq) * QKVC + qoff + t * 16 + hh * 8];
            uint4 raw = *reinterpret_cast<const uint4*>(qp);
            union { uint32_t u[4]; short8 s; } qa;
            qa.u[0] = cvtpk(bflo(raw.x) * QS, bfhi(raw.x) * QS);
            qa.u[1] = cvtpk(bflo(raw.y) * QS, bfhi(raw.y) * QS);
            qa.u[2] = cvtpk(bflo(raw.z) * QS, bfhi(raw.z) * QS);
            qa.u[3] = cvtpk(bflo(raw.w) * QS, bfhi(raw.w) * QS);
            qs[t] = qa.s;
        }

        f32x16 acc = fz;
        f32x16 accS = fz;   // ones-MFMA row-sum accumulator

        #pragma unroll 4
        for (int s = 0; s < 16; ++s) {
            const short8 a0 = *reinterpret_cast<const short8*>(pK + s * 2048 + ca0);
            const short8 a1 = *reinterpret_cast<const short8*>(pK + s * 2048 + ca1);
            __builtin_amdgcn_s_setprio(1);
            f32x16 st = __builtin_amdgcn_mfma_f32_32x32x16_bf16(a0, qs[0], fz, 0, 0, 0);
            st = __builtin_amdgcn_mfma_f32_32x32x16_bf16(a1, qs[1], st, 0, 0, 0);
            __builtin_amdgcn_s_setprio(0);

            float p[16];
            #pragma unroll
            for (int r = 0; r < 16; ++r) p[r] = exp2f(st[r]);

            uint32_t X[8];
            #pragma unroll
            for (int gg = 0; gg < 4; ++gg) {
                X[2 * gg + 0] = cvtpk(p[4 * gg + 0], p[4 * gg + 1]);
                X[2 * gg + 1] = cvtpk(p[4 * gg + 2], p[4 * gg + 3]);
            }
            const int k0 = s * 32;
            #pragma unroll
            for (int u = 0; u < 2; ++u) {
                uint32_t w0 = X[4 * u + 0], w2 = X[4 * u + 2];
                uint32_t w1 = X[4 * u + 1], w3 = X[4 * u + 3];
                plswap(w0, w2);
                plswap(w1, w3);
                union { uint32_t u4[4]; short8 s; } pf;
                pf.u4[0] = w0; pf.u4[1] = w1; pf.u4[2] = w2; pf.u4[3] = w3;
                const short8 vf = *reinterpret_cast<const short8*>(
                    pVT + ((k0 * 2 + u * 32) ^ vtx));
                __builtin_amdgcn_s_setprio(1);
                acc = __builtin_amdgcn_mfma_f32_32x32x16_bf16(vf, pf.s, acc, 0, 0, 0);
                accS = __builtin_amdgcn_mfma_f32_32x32x16_bf16(ones, pf.s, accS, 0, 0, 0);
                __builtin_amdgcn_s_setprio(0);
            }
        }

        float scl = r1 / accS[0];
        const ushort* ap = &Abuf[(size_t)(b * Nn + nq) * DIMc + qoff];
        ushort* hp = &Hb[(size_t)(b * Nn + nq) * DIMc + qoff];
        #pragma unroll
        for (int gg = 0; gg < 4; ++gg) {
            int d0 = 8 * gg + 4 * hh;
            uint2 av = *reinterpret_cast<const uint2*>(&ap[d0]);
            float v0 = hswish(bflo(av.x) + acc[4 * gg + 0] * scl);
            float v1 = hswish(bfhi(av.x) + acc[4 * gg + 1] * scl);
            float v2 = hswish(bflo(av.y) + acc[4 * gg + 2] * scl);
            float v3 = hswish(bfhi(av.y) + acc[4 * gg + 3] * scl);
            uint2 pk; pk.x = cvtpk(v0, v1); pk.y = cvtpk(v2, v3);
            *reinterpret_cast<uint2*>(&hp[d0]) = pk;
        }
    }
}

// ---------------- BatchNorm normalize (x4 vectorized) ----------------
__global__ __launch_bounds__(256) void bnnorm_kernel(
    const float* __restrict__ Y, const float* __restrict__ stats,
    const float* __restrict__ g, const float* __restrict__ bta,
    float* __restrict__ out)
{
    int i4 = (blockIdx.x * 256 + threadIdx.x) * 4;
    int c = i4 & 255;
    float4 y = *reinterpret_cast<const float4*>(&Y[i4]);
    float4 mu = *reinterpret_cast<const float4*>(&stats[c]);
    float4 s2 = *reinterpret_cast<const float4*>(&stats[256 + c]);
    float4 gg = *reinterpret_cast<const float4*>(&g[c]);
    float4 bb = *reinterpret_cast<const float4*>(&bta[c]);
    const float inv_m = 1.f / (float)Mrows;
    float4 o;
    {
        float m = mu.x * inv_m, v = s2.x * inv_m - m * m;
        o.x = (y.x - m) * rsqrtf(v + 1e-5f) * gg.x + bb.x;
        m = mu.y * inv_m; v = s2.y * inv_m - m * m;
        o.y = (y.y - m) * rsqrtf(v + 1e-5f) * gg.y + bb.y;
        m = mu.z * inv_m; v = s2.z * inv_m - m * m;
        o.z = (y.z - m) * rsqrtf(v + 1e-5f) * gg.z + bb.z;
        m = mu.w * inv_m; v = s2.w * inv_m - m * m;
        o.w = (y.w - m) * rsqrtf(v + 1e-5f) * gg.w + bb.w;
    }
    *reinterpret_cast<float4*>(&out[i4]) = o;
}

// ---------------- launch ----------------
extern "C" void kernel_launch(void* const* d_in, const int* in_sizes, int n_in,
                              void* d_out, int out_size, void* d_ws, size_t ws_size,
                              hipStream_t stream)
{
    const float* x      = (const float*)d_in[0];
    const float* w_qkv  = (const float*)d_in[1];
    const float* b_qkv  = (const float*)d_in[2];
    const float* w_out  = (const float*)d_in[3];
    const float* b_out  = (const float*)d_in[4];
    const float* bn_g   = (const float*)d_in[5];
    const float* bn_b   = (const float*)d_in[6];
    const float* pconv_w = (const float*)d_in[7];
    const float* pconv_b = (const float*)d_in[8];
    const float* fc_w   = (const float*)d_in[9];
    const float* dep_w  = (const float*)d_in[10];
    const float* dep_b  = (const float*)d_in[11];
    const float* rate1  = (const float*)d_in[12];
    const float* rate2  = (const float*)d_in[13];
    float* out = (float*)d_out;

    char* ws = (char*)d_ws;
    ushort* qvb   = (ushort*)(ws);                           // 32 MB [0,32M)
    ushort* Hb    = (ushort*)(ws + (32u << 20));             // 16 MB [32M,48M)
    ushort* Abuf  = (ushort*)(ws + (48u << 20));             // 16 MB [48M,64M)
    ushort* xb    = (ushort*)(ws + (64u << 20));             // 16 MB [64M,80M)
    float*  Ybuf  = (float*)(ws + (96u << 20));              // 32 MB [96M,128M)
    float*  stats = (float*)(ws + (128u << 20));             // 2 KB
    ushort* Wt1   = (ushort*)(ws + (128u << 20) + 4096);     // 256 KB
    ushort* Wt2   = (ushort*)(ws + (128u << 20) + 4096 + (256u << 10)); // 128 KB
    uint32_t* Wp  = (uint32_t*)(ws + (128u << 20) + 4096 + (384u << 10)); // 36 KB

    // 0. prep: bf16 weights (transposed), packed composed conv weights, bf16 x
    wtconv_kernel<<<(512 * 256) / 256, 256, 0, stream>>>(w_qkv, Wt1, 256, 512);
    wtconv_kernel<<<(256 * 256) / 256, 256, 0, stream>>>(w_out, Wt2, 256, 256);
    weff_kernel<<<36, 256, 0, stream>>>(dep_w, fc_w, Wp);
    cvtbf_kernel<<<(Mrows * 256 / 8) / 256, 256, 0, stream>>>(x, xb);

    // 1. qvb = bf16(x @ w_qkv + b_qkv)
    hgemm_kernel<true, false><<<dim3(4, 256), 256, 0, stream>>>(
        xb, Wt1, b_qkv, qvb, nullptr, Mrows, 512, 256);

    // 2. Abuf = rate2 * out_conv  (first writer, pure store)
    convbranch_kernel<<<2048, 256, 0, stream>>>(qvb, Wp, dep_b, rate2, Abuf);

    // 3. Abuf += v_conv  (coalesced bf16 RMW)
    vconv_kernel<<<(Mrows * 128) / 256, 256, 0, stream>>>(qvb, pconv_w, pconv_b, Abuf);

    // 4. MFMA window attention; epilogue writes Hb = bf16(hswish(A + rate1*o))
    attn_mfma_kernel<<<512, 512, 0, stream>>>(qvb, rate1, Abuf, Hb);

    // 5. Y = Hb @ w_out + b_out, with fused BN stats
    hipMemsetAsync(stats, 0, 2 * 256 * sizeof(float), stream);
    hgemm_kernel<false, true><<<dim3(2, 256), 256, 0, stream>>>(
        Hb, Wt2, b_out, Ybuf, stats, Mrows, 256, 256);

    // 6. BatchNorm normalize
    bnnorm_kernel<<<(Mrows * 256 / 4) / 256, 256, 0, stream>>>(Ybuf, stats, bn_g, bn_b, out);
}